// Round 2
// baseline (467.289 us; speedup 1.0000x reference)
//
#include <hip/hip_runtime.h>
#include <hip/hip_bf16.h>

typedef unsigned short u16;
typedef __attribute__((ext_vector_type(8))) short bf16x8;    // 8 bf16 in 4 VGPRs
typedef __attribute__((ext_vector_type(16))) float f32x16;

static __device__ __forceinline__ u16 f2bf(float f) {
    unsigned u = __float_as_uint(f);
    unsigned r = (u + 0x7fffu + ((u >> 16) & 1u)) >> 16;   // RNE
    return (u16)r;
}
static __device__ __forceinline__ float bf2f(u16 u) {
    return __uint_as_float(((unsigned)u) << 16);
}

static __device__ __forceinline__ void async_copy16(const void* gptr, void* lptr) {
    __builtin_amdgcn_global_load_lds(
        (const __attribute__((address_space(1))) void*)gptr,
        (__attribute__((address_space(3))) void*)lptr, 16, 0, 0);
}

// ---------------------------------------------------------------------------
// fp32 -> bf16 for all three inputs in ONE launch.
// ---------------------------------------------------------------------------
__global__ __launch_bounds__(256)
void cvt_all(const float* __restrict__ a, const float* __restrict__ b,
             const float* __restrict__ c,
             u16* __restrict__ oa, u16* __restrict__ ob, u16* __restrict__ oc) {
    int blk = blockIdx.x;
    const float* src; u16* dst; long base;
    if (blk < 16384)      { src = a; dst = oa; base = blk; }
    else if (blk < 28672) { src = b; dst = ob; base = blk - 16384; }
    else                  { src = c; dst = oc; base = blk - 28672; }
    long i = (base * 256 + threadIdx.x) * 4;
    float4 f = *(const float4*)(src + i);
    u16 o[4] = { f2bf(f.x), f2bf(f.y), f2bf(f.z), f2bf(f.w) };
    *(uint2*)(dst + i) = *(const uint2*)o;
}

// ---------------------------------------------------------------------------
// C[m,n] = sum_k A[m,k] * B[n,k]   (row-major, K contiguous — "BT" gemm)
//
// 256x256 tile, 512 threads = 8 waves (2M x 4N), wave tile 128x64 as 4x2 of
// mfma_f32_32x32x16_bf16 (layouts proven in the R0 kernel).
//
// R2 restructure: ONE-PHASE-AHEAD fragment prefetch. R1's phase model fit
// measured 1206 cyc/phase = 621 (MFMA) + 565 (same-phase LDS reads,
// serialized) — reads were lgkm(0)-waited immediately after issue. Now:
//   BK=32, FOUR LDS buffers (4 x 32KB = 128KB), rotation mod 4:
//     iter i: read buf[i%4] (2 phases: ks0, ks1), stage tile i+3 -> buf[(i+3)%4]
//   phase = { 6 ds_read_b128 for NEXT phase's fragments || 2 global_load_lds
//             || 8 MFMA on PREVIOUS phase's fragments }.
//   The compiler's implicit lgkmcnt before the MFMA cluster waits only the
//   previous phase's 6 reads, which drained under a full MFMA cluster.
//   Boundary per iter: s_waitcnt vmcnt(4) (counted, NEVER 0 — leaves this
//   iter's 4 stage-copies in flight) + s_barrier.
//
// Pipeline safety (stage-ahead = 3 tiles, 4 copies/thread/iter):
//   - tile T staged at iter T-3; vmcnt(4) at boundary j confirms iter j-1's
//     stages => tile T confirmed at end of boundary T-2; the cross-boundary
//     read of buf[(i+1)%4] issued late in body i (tile i+1, confirmed at
//     boundary i-1) is always safe.
//   - all reads of a buffer are lgkm-completed (by their consuming MFMA)
//     BEFORE the barrier that precedes any re-staging of that buffer;
//     within a body, read targets {i, i+1} and stage target {i+3} are
//     disjoint mod 4. Barrier keeps wave drift < 1 iteration.
//   - tail: stage source k wraps to 0 (junk staged, never consumed).
//
// LDS swizzle (BK=32 -> 4 chunks/row): phys slot = kc ^ ((row>>1)&3) gives
// uniform 8 lanes per 4-bank group per ds_read_b128 (structural minimum).
// Swizzle pre-applied on the GLOBAL source at staging (global_load_lds needs
// linear lane*16B dests); fragment reads un-swizzle with the same XOR.
//
// M mult of 256, N mult of 256, K mult of 128, gridDim.x mult of 8, K>=128.
// ---------------------------------------------------------------------------
template<bool BF16_OUT>
__global__ __launch_bounds__(512, 2)
void gemm_bt8(const u16* __restrict__ A, const u16* __restrict__ B,
              void* __restrict__ Cout, int M, int N, int K) {
    __shared__ __align__(16) u16 lds[65536];   // 128 KiB = 4 bufs x (A 8K | B 8K) u16

    const int t    = threadIdx.x;              // 0..511
    const int lane = t & 63;
    const int wm   = (t >> 6) >> 2;            // 0..1
    const int wn   = (t >> 6) & 3;             // 0..3
    const int l32  = lane & 31;
    const int hi   = lane >> 5;                // 0..1

    // XCD-aware panel remap (bijective since gridDim.x % 8 == 0)
    const int id   = blockIdx.y * gridDim.x + blockIdx.x;
    const int cpx  = gridDim.x >> 3;
    const int bx   = (id & 7) * cpx + ((id >> 3) % cpx);
    const int by   = (id >> 3) / cpx;
    const long rowA = (long)by * 256;
    const long rowB = (long)bx * 256;

    // ---- staging source pointers (pre-swizzled global source) ----
    // thread t covers chunk c = t and c = t+512 of a 1024-chunk (256x32) tile:
    // phys (row, slot) = (c>>2, c&3); logical kc = slot ^ ((row>>1)&3).
    // row(t+512) = row(t)+128 -> same kc for both copies.
    const int sr  = t >> 2;                               // 0..127
    const int kcs = ((t & 3) ^ ((sr >> 1) & 3)) * 8;
    const u16* Asrc0 = A + (rowA + sr) * (long)K + kcs;
    const u16* Asrc1 = Asrc0 + 128 * (long)K;
    const u16* Bsrc0 = B + (rowB + sr) * (long)K + kcs;
    const u16* Bsrc1 = Bsrc0 + 128 * (long)K;
    u16* const dA = lds + t * 8;               // + bufo       (linear dest)
    u16* const dB = lds + 8192 + t * 8;        // + bufo

    // ---- fragment read offsets (u16 units) ----
    // A frag (m): row = wm*128 + m*32 + l32, chunk kc = ks*2 + hi,
    //             phys slot = kc ^ ((row>>1)&3) = kc ^ ((l32>>1)&3)
    const int sw = (l32 >> 1) & 3;
    const int c0 = (hi ^ sw) * 8;              // ks=0 chunk byte-offset/2
    const int c1 = ((2 + hi) ^ sw) * 8;        // ks=1
    const int aO = (wm * 128 + l32) * 32;      // + m*1024 + c
    const int bO = 8192 + (wn * 64 + l32) * 32;// + n*1024 + c

    bf16x8 afA[4], bgA[2], afB[4], bgB[2];
    f32x16 acc[4][2] = {};

    auto STAGE_A = [&](int bufo, int kk) {
        async_copy16(Asrc0 + kk, dA + bufo);
        async_copy16(Asrc1 + kk, dA + bufo + 4096);
    };
    auto STAGE_B = [&](int bufo, int kk) {
        async_copy16(Bsrc0 + kk, dB + bufo);
        async_copy16(Bsrc1 + kk, dB + bufo + 4096);
    };
    auto LOADS = [&](int bufo, int cOff, bf16x8* af, bf16x8* bg) {
#pragma unroll
        for (int m = 0; m < 4; m++)
            af[m] = *(const bf16x8*)(lds + bufo + aO + m * 1024 + cOff);
#pragma unroll
        for (int n = 0; n < 2; n++)
            bg[n] = *(const bf16x8*)(lds + bufo + bO + n * 1024 + cOff);
    };
    auto MF = [&](bf16x8* af, bf16x8* bg) {
        __builtin_amdgcn_s_setprio(1);
#pragma unroll
        for (int m = 0; m < 4; m++)
#pragma unroll
            for (int n = 0; n < 2; n++)
                acc[m][n] = __builtin_amdgcn_mfma_f32_32x32x16_bf16(
                    af[m], bg[n], acc[m][n], 0, 0, 0);
        __builtin_amdgcn_s_setprio(0);
    };

    // ---- prologue: stage tiles 0,1,2 -> bufs 0,1,2; confirm tiles 0,1 ----
    STAGE_A(0, 0);          STAGE_B(0, 0);
    STAGE_A(16384, 32);     STAGE_B(16384, 32);
    STAGE_A(32768, 64);     STAGE_B(32768, 64);
    asm volatile("s_waitcnt vmcnt(4)" ::: "memory");   // tiles 0,1 landed
    __builtin_amdgcn_s_barrier();
    LOADS(0, c0, afA, bgA);                            // tile 0, ks0

    const int NT = K >> 5;                             // K/32 tiles
#pragma unroll 4
    for (int i = 0; i < NT; i++) {
        const int bufR = (i & 3) << 14;                // read buffer
        const int bufN = ((i + 1) & 3) << 14;          // next tile's buffer
        const int bufS = ((i + 3) & 3) << 14;          // stage target
        int kk = (i + 3) << 5; if (kk >= K) kk = 0;    // tail: junk, never read
        // phase 0: prefetch ks1 frags; stage A half; MFMA ks0
        LOADS(bufR, c1, afB, bgB);
        STAGE_A(bufS, kk);
        MF(afA, bgA);
        // phase 1: prefetch next tile's ks0 frags; stage B half; MFMA ks1
        LOADS(bufN, c0, afA, bgA);
        STAGE_B(bufS, kk);
        MF(afB, bgB);
        // boundary: counted wait (2-iter-old stages confirmed), barrier
        asm volatile("s_waitcnt vmcnt(4)" ::: "memory");
        __builtin_amdgcn_s_barrier();
    }
    // drain in-flight LDS-targeted loads before LDS dealloc at endpgm
    asm volatile("s_waitcnt vmcnt(0)" ::: "memory");

    // ---- epilogue: 32x32 C/D layout col=lane&31, row=(r&3)+8*(r>>2)+4*hi ----
#pragma unroll
    for (int mi = 0; mi < 4; mi++) {
#pragma unroll
        for (int nj = 0; nj < 2; nj++) {
#pragma unroll
            for (int r = 0; r < 16; r++) {
                int rowt = (r & 3) + 8 * (r >> 2) + 4 * hi;
                long m = rowA + wm * 128 + mi * 32 + rowt;
                long n = rowB + wn * 64 + nj * 32 + l32;
                float v = acc[mi][nj][r];
                if (BF16_OUT) ((u16*)Cout)[m * N + n] = f2bf(v);
                else          ((float*)Cout)[m * N + n] = v;
            }
        }
    }
}

// ---------------------------------------------------------------------------
// Fused Bx-product + depthwise causal conv(L=3) + C-gate.
// BCx: (8192, 6144) bf16 rows = [B(0:2048) | C(2048:4096) | x(4096:6144)]
// y[s,h] = C[s,h] * ( w[h,0]*Bx[s-2,h] + w[h,1]*Bx[s-1,h] + w[h,2]*Bx[s,h] )
// batch boundary: s resets every 4096 rows (zero left-pad per batch)
// ---------------------------------------------------------------------------
union U16x8 { uint4 v; u16 u[8]; };

__global__ __launch_bounds__(256)
void conv_fuse(const u16* __restrict__ BCx, const float* __restrict__ cw,
               u16* __restrict__ y) {
    const int row = blockIdx.x;            // 0..8191
    const int h0  = threadIdx.x * 8;       // 256*8 = 2048
    const int sl  = row & 4095;
    const u16* r0 = BCx + (long)row * 6144;

    U16x8 B0, X0, C0, B1, X1, B2, X2;
    B0.v = *(const uint4*)(r0 + h0);
    C0.v = *(const uint4*)(r0 + 2048 + h0);
    X0.v = *(const uint4*)(r0 + 4096 + h0);
    if (sl >= 1) {
        B1.v = *(const uint4*)(r0 - 6144 + h0);
        X1.v = *(const uint4*)(r0 - 6144 + 4096 + h0);
    } else { B1.v = make_uint4(0,0,0,0); X1.v = make_uint4(0,0,0,0); }
    if (sl >= 2) {
        B2.v = *(const uint4*)(r0 - 12288 + h0);
        X2.v = *(const uint4*)(r0 - 12288 + 4096 + h0);
    } else { B2.v = make_uint4(0,0,0,0); X2.v = make_uint4(0,0,0,0); }

    U16x8 o;
#pragma unroll
    for (int i = 0; i < 8; i++) {
        int h = h0 + i;
        float bx0 = bf2f(B0.u[i]) * bf2f(X0.u[i]);   // tap l=2 (current)
        float bx1 = bf2f(B1.u[i]) * bf2f(X1.u[i]);   // tap l=1 (s-1)
        float bx2 = bf2f(B2.u[i]) * bf2f(X2.u[i]);   // tap l=0 (s-2)
        float v = cw[h*3+2] * bx0 + cw[h*3+1] * bx1 + cw[h*3] * bx2;
        o.u[i] = f2bf(v * bf2f(C0.u[i]));
    }
    *(uint4*)(y + (long)row * 2048 + h0) = o.v;
}

// ---------------------------------------------------------------------------
extern "C" void kernel_launch(void* const* d_in, const int* in_sizes, int n_in,
                              void* d_out, int out_size, void* d_ws, size_t ws_size,
                              hipStream_t stream) {
    const float* hs   = (const float*)d_in[0];   // (2,4096,2048)
    const float* Win  = (const float*)d_in[1];   // (6144,2048)
    const float* cw   = (const float*)d_in[2];   // (2048,1,3)
    const float* Wout = (const float*)d_in[3];   // (2048,2048)
    float* out = (float*)d_out;                  // (2,4096,2048) fp32

    char* ws = (char*)d_ws;
    u16* hsb   = (u16*)(ws);                     //  33,554,432 B
    u16* Winb  = (u16*)(ws +  33554432);         //  25,165,824 B
    u16* Woutb = (u16*)(ws +  58720256);         //   8,388,608 B
    u16* bcx   = (u16*)(ws +  67108864);         // 100,663,296 B
    u16* yb    = (u16*)(ws + 167772160);         //  33,554,432 B  (end 201,326,592)

    cvt_all<<<32768, 256, 0, stream>>>(hs, Win, Wout, hsb, Winb, Woutb);

    // BCx = hs @ Win^T : M=8192, N=6144, K=2048  (grid 24x32 = 768 blocks)
    gemm_bt8<true ><<<dim3(24, 32), 512, 0, stream>>>(hsb, Winb, bcx, 8192, 6144, 2048);

    conv_fuse<<<8192, 256, 0, stream>>>(bcx, cw, yb);

    // out = y @ Wout^T : M=8192, N=2048, K=2048  (grid 8x32 = 256 blocks)
    gemm_bt8<false><<<dim3(8, 32), 512, 0, stream>>>(yb, Woutb, out, 8192, 2048, 2048);
}